// Round 2
// baseline (32.374 us; speedup 1.0000x reference)
//
#include <hip/hip_runtime.h>

#define BATCH 1024
#define NANCH 3125
#define LAMB  5.0f
#define SPLIT 4
#define CHUNK ((NANCH + SPLIT - 1) / SPLIT)   // 782

__device__ __forceinline__ float wave_red_f(float v) {
    #pragma unroll
    for (int o = 32; o > 0; o >>= 1) v += __shfl_down(v, o, 64);
    return v;
}

// grid = BATCH*SPLIT, block = 256. Each block reduces a chunk of one batch row
// into 5 partial sums: {ce_pos, ce_neg, sl, pos_cnt, neg_cnt}.
__global__ __launch_bounds__(256) void partial_kernel(
    const float* __restrict__ c_pred,    // [B,N,2]
    const float* __restrict__ r_pred,    // [B,N,4]
    const float* __restrict__ r_target,  // [B,N,4]
    const int*   __restrict__ label,     // [B,N]
    float*       __restrict__ partial)   // [B*SPLIT, 5]
{
    const int blk = blockIdx.x;
    const int b   = blk / SPLIT;
    const int s   = blk % SPLIT;
    const int tid = threadIdx.x;

    const float2* c2 = (const float2*)(c_pred   + (size_t)b * NANCH * 2);
    const float4* rp = (const float4*)(r_pred   + (size_t)b * NANCH * 4);
    const float4* rt = (const float4*)(r_target + (size_t)b * NANCH * 4);
    const int*    lb = label + (size_t)b * NANCH;

    const int end = min((s + 1) * CHUNK, NANCH);

    float cp = 0.f, cn = 0.f, sl = 0.f, pc = 0.f, nc = 0.f;

    for (int i = s * CHUNK + tid; i < end; i += 256) {
        const int    l = lb[i];
        const float2 c = c2[i];
        const float4 p = rp[i];
        const float4 t = rt[i];

        const float isp = (l == 1) ? 1.f : 0.f;
        const float isn = (l == 0) ? 1.f : 0.f;

        // log-sum-exp over 2 logits
        const float m   = fmaxf(c.x, c.y);
        const float lse = m + log1pf(__expf(-fabsf(c.x - c.y)));

        pc += isp;
        nc += isn;
        cp += isp * (lse - c.y);   // -logp[...,1]
        cn += isn * (lse - c.x);   // -logp[...,0]

        float s4 = 0.f, d, a;
        d = p.x - t.x; a = fabsf(d); s4 += (a < 1.f) ? 0.5f * d * d : a - 0.5f;
        d = p.y - t.y; a = fabsf(d); s4 += (a < 1.f) ? 0.5f * d * d : a - 0.5f;
        d = p.z - t.z; a = fabsf(d); s4 += (a < 1.f) ? 0.5f * d * d : a - 0.5f;
        d = p.w - t.w; a = fabsf(d); s4 += (a < 1.f) ? 0.5f * d * d : a - 0.5f;
        sl += isp * s4 * 0.25f;
    }

    cp = wave_red_f(cp);
    cn = wave_red_f(cn);
    sl = wave_red_f(sl);
    pc = wave_red_f(pc);
    nc = wave_red_f(nc);

    __shared__ float sm[5][4];
    const int wid = tid >> 6, lane = tid & 63;
    if (lane == 0) {
        sm[0][wid] = cp; sm[1][wid] = cn; sm[2][wid] = sl;
        sm[3][wid] = pc; sm[4][wid] = nc;
    }
    __syncthreads();
    if (tid == 0) {
        float v0 = 0.f, v1 = 0.f, v2 = 0.f, v3 = 0.f, v4 = 0.f;
        #pragma unroll
        for (int w = 0; w < 4; ++w) {
            v0 += sm[0][w]; v1 += sm[1][w]; v2 += sm[2][w];
            v3 += sm[3][w]; v4 += sm[4][w];
        }
        float* o = partial + (size_t)blk * 5;
        o[0] = v0; o[1] = v1; o[2] = v2; o[3] = v3; o[4] = v4;
    }
}

// grid = 1, block = 256. Combine SPLIT partials per batch, compute per-batch
// contributions, reduce over batches, emit (c_loss, r_loss, t_loss).
__global__ __launch_bounds__(256) void finalize_kernel(
    const float* __restrict__ partial,   // [B*SPLIT, 5]
    float*       __restrict__ out)       // [3]
{
    const int tid = threadIdx.x;
    float csum = 0.f, rsum = 0.f;

    for (int b = tid; b < BATCH; b += 256) {
        float cp = 0.f, cn = 0.f, sl = 0.f, pc = 0.f, nc = 0.f;
        #pragma unroll
        for (int s = 0; s < SPLIT; ++s) {
            const float* p = partial + ((size_t)b * SPLIT + s) * 5;
            cp += p[0]; cn += p[1]; sl += p[2]; pc += p[3]; nc += p[4];
        }
        const bool haspos = (pc > 0.5f);
        const float pos_mean = haspos ? cp / fmaxf(pc, 1.f) : 0.f;
        const float neg_mean = cn / fmaxf(nc, 1.f);
        csum += (pos_mean + neg_mean) * 0.5f;
        rsum += haspos ? sl / fmaxf(pc, 1.f) : 0.f;
    }

    csum = wave_red_f(csum);
    rsum = wave_red_f(rsum);

    __shared__ float s_c[4], s_r[4];
    const int wid = tid >> 6, lane = tid & 63;
    if (lane == 0) { s_c[wid] = csum; s_r[wid] = rsum; }
    __syncthreads();
    if (tid == 0) {
        float cs = 0.f, rs = 0.f;
        #pragma unroll
        for (int w = 0; w < 4; ++w) { cs += s_c[w]; rs += s_r[w]; }
        const float c_loss = cs / (float)BATCH;
        const float r_loss = rs / (float)BATCH;
        out[0] = c_loss;
        out[1] = r_loss;
        out[2] = c_loss + LAMB * r_loss;
    }
}

extern "C" void kernel_launch(void* const* d_in, const int* in_sizes, int n_in,
                              void* d_out, int out_size, void* d_ws, size_t ws_size,
                              hipStream_t stream) {
    const float* c_pred   = (const float*)d_in[0];
    const float* r_pred   = (const float*)d_in[1];
    const float* r_target = (const float*)d_in[2];
    const int*   label    = (const int*)d_in[3];
    float*       out      = (float*)d_out;
    float*       partial  = (float*)d_ws;   // BATCH*SPLIT*5 floats = 80 KiB

    partial_kernel<<<BATCH * SPLIT, 256, 0, stream>>>(c_pred, r_pred, r_target, label, partial);
    finalize_kernel<<<1, 256, 0, stream>>>(partial, out);
}